// Round 19
// baseline (223.232 us; speedup 1.0000x reference)
//
#include <hip/hip_runtime.h>
#include <stdint.h>

#define NROWS 16384
#define DIM 512
#define CSPLIT 8
#define COLS_PER_SPLIT (NROWS / CSPLIT)   // 2048
#define BM 256                            // rows per block (4 waves x 64)
#define NT 32                             // cols per tile
#define BK 256                            // k per K-step
#define NTILES (COLS_PER_SPLIT / NT)      // 64
#define PPT (DIM / BK)                    // 2 K-steps per tile
#define NPHASE (NTILES * PPT)             // 128
#define PMASK (NPHASE - 1)

using i32x4  = __attribute__((ext_vector_type(4))) int;
using i32x16 = __attribute__((ext_vector_type(16))) int;
using char8  = __attribute__((ext_vector_type(8))) signed char;

#define AS1 __attribute__((address_space(1)))
#define AS3 __attribute__((address_space(3)))

// ---------------- Kernel A: L2-normalize + FIXED-scale i8 quantize ----------
__global__ __launch_bounds__(256) void knorm(const float* __restrict__ in,
                                             signed char* __restrict__ xq,
                                             float* __restrict__ inv) {
  const int lane = threadIdx.x & 63;
  const int wave = threadIdx.x >> 6;
  const int row = blockIdx.x * 4 + wave;
  const float4* p = (const float4*)(in + (size_t)row * DIM + lane * 8);
  const float4 a = p[0], b = p[1];
  float ss = a.x*a.x + a.y*a.y + a.z*a.z + a.w*a.w
           + b.x*b.x + b.y*b.y + b.z*b.z + b.w*b.w;
  #pragma unroll
  for (int m = 32; m >= 1; m >>= 1) ss += __shfl_xor(ss, m, 64);
  const float iv = 1.0f / fmaxf(sqrtf(ss), 1e-8f);
  const float s508 = iv * 508.0f;
  char8 q;
  q[0] = (signed char)(int)rintf(fminf(fmaxf(a.x * s508, -127.f), 127.f));
  q[1] = (signed char)(int)rintf(fminf(fmaxf(a.y * s508, -127.f), 127.f));
  q[2] = (signed char)(int)rintf(fminf(fmaxf(a.z * s508, -127.f), 127.f));
  q[3] = (signed char)(int)rintf(fminf(fmaxf(a.w * s508, -127.f), 127.f));
  q[4] = (signed char)(int)rintf(fminf(fmaxf(b.x * s508, -127.f), 127.f));
  q[5] = (signed char)(int)rintf(fminf(fmaxf(b.y * s508, -127.f), 127.f));
  q[6] = (signed char)(int)rintf(fminf(fmaxf(b.z * s508, -127.f), 127.f));
  q[7] = (signed char)(int)rintf(fminf(fmaxf(b.w * s508, -127.f), 127.f));
  *(char8*)(xq + (size_t)row * DIM + lane * 8) = q;
  if (lane == 0) inv[row] = iv;
}

// ---------------- Kernel B: i8 Gram (32x32x32 MFMA) + integer argmax --------
// R10 sync skeleton (128 phases, vmcnt(4)+1 barrier each, depth-3, 2 stage
// loads/step) with the 32x32x32 i8 MFMA (measured 4404 vs 3944 TOPS, half the
// instruction count). 64 rows/wave = 2 rf x 32; NT=32, BK=256. Paired-column
// LDS swizzle: byte(col,j16) = (col>>1)*512 + ((j16*2 + (col&1)) ^ ((col>>1)&15))*16.
__global__ __launch_bounds__(256, 2) void kdots(const signed char* __restrict__ xq,
                                                uint32_t* __restrict__ keys) {
  const int tid  = threadIdx.x;
  const int lane = tid & 63;
  const int wave = tid >> 6;
  const int bx = blockIdx.x;
  const int cs = bx & (CSPLIT - 1);     // same-cs blocks land on same XCD (%8)
  const int rb = bx >> 3;
  const int rowbase  = rb * BM + wave * 64;
  const int colsplit = cs * COLS_PER_SPLIT;
  // diag falls in tiles td0, td0+1 (32-col tiles vs 64-row wave), or never
  const int td0 = ((rowbase >> 11) == cs) ? ((rowbase - colsplit) >> 5)
                                          : -0x40000000;
  const int c31 = lane & 31;
  const int hi2 = lane >> 5;            // 0/1
  const int rb0 = rowbase + hi2 * 4;          // rf=0 row base for this lane
  const int rb1 = rowbase + 32 + hi2 * 4;     // rf=1

  __shared__ signed char lds[4][NT * BK];   // 4 x 8 KB

  // ---- A fragments: 2 rowfrags x 16 kfrags(K=32) x 4 regs = 128 VGPR ----
  // layout per mfma_32x32x32_i8: row = lane&31, k = (lane>>5)*16 + e
  i32x4 areg[2][16];
  #pragma unroll
  for (int rf = 0; rf < 2; ++rf) {
    const signed char* ap =
        xq + (size_t)(rowbase + rf * 32 + c31) * DIM + hi2 * 16;
    #pragma unroll
    for (int kf = 0; kf < 16; ++kf)
      areg[rf][kf] = *(const i32x4*)(ap + kf * 32);
  }

  uint32_t rkey0[16], rkey1[16];
  #pragma unroll
  for (int r = 0; r < 16; ++r) { rkey0[r] = 0u; rkey1[r] = 0u; }

  i32x16 acc0, acc1;   // zero-C'd at each tile's kb0; EPI reads next tile

  // stage one 8 KB buffer (32 cols x 256 k): 2 global_load_lds(16B)/thread.
  // u -> pair p=u>>5, swizzled slot sw=u&31; s = sw ^ (p&15); col=p*2+(s&1),
  // k-chunk j=s>>1. Source = 256B-contiguous column strips (coalesced).
  auto STAGE = [&](int buf, int p) {
    const int tt = p >> 1, kb2 = p & 1;
    #pragma unroll
    for (int h = 0; h < 2; ++h) {
      const int u = h * 256 + tid;
      const int pp = u >> 5;
      const int s = (u & 31) ^ (pp & 15);
      const int col = pp * 2 + (s & 1);
      const signed char* g = xq + (size_t)(colsplit + tt * NT + col) * DIM
                           + kb2 * BK + ((s >> 1) << 4);
      char* l = ((char*)&lds[buf][0]) + u * 16;
      __builtin_amdgcn_global_load_lds((AS1 const void*)g, (AS3 void*)l, 16, 0, 0);
    }
  };

  __syncthreads();   // drains areg loads (vmcnt -> 0)
  STAGE(0, 0); STAGE(1, 1); STAGE(2, 2);   // depth-3 prologue: 6 outstanding

  // ds_read offsets: lane reads col=c31, 16B at k=kk*32+hi2*16 ->
  // q=(c31)>>1, m=hi2*2+(c31... see derivation; kk+4 = +256 (bit4 of slot).
  const int q = c31 >> 1;
  const int m = (hi2 << 1) | (lane & 1);
  const int ro0 = q * 512 + (((0  + m) ^ q) << 4);
  const int ro1 = q * 512 + (((4  + m) ^ q) << 4);
  const int ro2 = q * 512 + (((8  + m) ^ q) << 4);
  const int ro3 = q * 512 + (((12 + m) ^ q) << 4);

#define EPI(ACC, RK, RBQ)                                                      \
  do {                                                                         \
    const uint32_t k0c = 0x80000000u + 2047u - (uint32_t)(pcolb + c31);        \
    _Pragma("unroll")                                                          \
    for (int r = 0; r < 16; ++r) {                                             \
      uint32_t key = ((uint32_t)(ACC[r] >> 3) << 11) + k0c;                    \
      if (dg && (gcolp == (RBQ) + (r & 3) + 8 * (r >> 2))) key = 0u;           \
      RK[r] = RK[r] > key ? RK[r] : key;                                       \
    }                                                                          \
  } while (0)

// 4 MFMAs: both accs accumulate kk=KA (FA) then kk=KA+1 (FB)
#define CL4(KA, FA, FB)                                                        \
  __builtin_amdgcn_s_setprio(1);                                               \
  acc0 = __builtin_amdgcn_mfma_i32_32x32x32_i8(areg[0][KA], FA, acc0, 0,0,0);  \
  acc1 = __builtin_amdgcn_mfma_i32_32x32x32_i8(areg[1][KA], FA, acc1, 0,0,0);  \
  acc0 = __builtin_amdgcn_mfma_i32_32x32x32_i8(areg[0][(KA)+1], FB, acc0, 0,0,0);\
  acc1 = __builtin_amdgcn_mfma_i32_32x32x32_i8(areg[1][(KA)+1], FB, acc1, 0,0,0);\
  __builtin_amdgcn_s_setprio(0);

#define WAITB                                                                  \
  asm volatile("s_waitcnt vmcnt(4)" ::: "memory");                             \
  __builtin_amdgcn_s_barrier();                                                \
  asm volatile("" ::: "memory");

// kb=0 K-step of tile T reading buf B: zero-C + EPI of tile T-1 interleaved
#define KSTEP0(T, B, SB, SP)                                                   \
  {                                                                            \
    WAITB                                                                      \
    STAGE(SB, (SP) & PMASK);                                                   \
    const char* base = (const char*)&lds[B][0];                                \
    i32x4 fA = *(const i32x4*)(base + ro0);                                    \
    i32x4 fB = *(const i32x4*)(base + ro1);                                    \
    i32x4 fC = *(const i32x4*)(base + ro2);                                    \
    i32x4 fD = *(const i32x4*)(base + ro3);                                    \
    const int pcolb = ((T) - 1) * NT;                                          \
    const bool dg = (unsigned)(((T) - 1) - td0) <= 1u;                         \
    const int gcolp = colsplit + pcolb + c31;                                  \
    if (T) EPI(acc0, rkey0, rb0);                                              \
    __builtin_amdgcn_s_setprio(1);                                             \
    acc0 = __builtin_amdgcn_mfma_i32_32x32x32_i8(areg[0][0], fA, Z16, 0,0,0);  \
    acc0 = __builtin_amdgcn_mfma_i32_32x32x32_i8(areg[0][1], fB, acc0, 0,0,0); \
    __builtin_amdgcn_s_setprio(0);                                             \
    if (T) EPI(acc1, rkey1, rb1);                                              \
    __builtin_amdgcn_s_setprio(1);                                             \
    acc1 = __builtin_amdgcn_mfma_i32_32x32x32_i8(areg[1][0], fA, Z16, 0,0,0);  \
    acc1 = __builtin_amdgcn_mfma_i32_32x32x32_i8(areg[1][1], fB, acc1, 0,0,0); \
    __builtin_amdgcn_s_setprio(0);                                             \
    fA = *(const i32x4*)(base + ro0 + 256);                                    \
    fB = *(const i32x4*)(base + ro1 + 256);                                    \
    CL4(2, fC, fD)                                                             \
    fC = *(const i32x4*)(base + ro2 + 256);                                    \
    fD = *(const i32x4*)(base + ro3 + 256);                                    \
    CL4(4, fA, fB)                                                             \
    CL4(6, fC, fD)                                                             \
  }

// kb=1 K-step reading buf B (kfrags 8..15)
#define KSTEP1(B, SB, SP)                                                      \
  {                                                                            \
    WAITB                                                                      \
    STAGE(SB, (SP) & PMASK);                                                   \
    const char* base = (const char*)&lds[B][0];                                \
    i32x4 fA = *(const i32x4*)(base + ro0);                                    \
    i32x4 fB = *(const i32x4*)(base + ro1);                                    \
    i32x4 fC = *(const i32x4*)(base + ro2);                                    \
    i32x4 fD = *(const i32x4*)(base + ro3);                                    \
    CL4(8, fA, fB)                                                             \
    fA = *(const i32x4*)(base + ro0 + 256);                                    \
    fB = *(const i32x4*)(base + ro1 + 256);                                    \
    CL4(10, fC, fD)                                                            \
    fC = *(const i32x4*)(base + ro2 + 256);                                    \
    fD = *(const i32x4*)(base + ro3 + 256);                                    \
    CL4(12, fA, fB)                                                            \
    CL4(14, fC, fD)                                                            \
  }

  const i32x16 Z16 = {0,0,0,0,0,0,0,0,0,0,0,0,0,0,0,0};

  for (int tp = 0; tp < NTILES; tp += 2) {
    const int P = 2 * tp;                 // P % 4 == 0
    // ---- tile tp: phases P (buf0), P+1 (buf1) ----
    KSTEP0(tp, 0, 3, P + 3)
    KSTEP1(1, 0, P + 4)
    // ---- tile tp+1: phases P+2 (buf2), P+3 (buf3) ----
    KSTEP0(tp + 1, 2, 1, P + 5)
    KSTEP1(3, 2, P + 6)
  }
  // ---- final epilogue for tile NTILES-1 ----
  {
    const int pcolb = (NTILES - 1) * NT;
    const bool dg = (unsigned)((NTILES - 1) - td0) <= 1u;
    const int gcolp = colsplit + pcolb + c31;
    EPI(acc0, rkey0, rb0);
    EPI(acc1, rkey1, rb1);
  }
#undef KSTEP0
#undef KSTEP1
#undef WAITB
#undef CL4
#undef EPI

  // ---- cross-lane key max over the 32-lane col dimension -------------------
  #pragma unroll
  for (int mm = 1; mm <= 16; mm <<= 1) {
    #pragma unroll
    for (int r = 0; r < 16; ++r) {
      uint32_t o = (uint32_t)__shfl_xor((int)rkey0[r], mm, 64);
      rkey0[r] = rkey0[r] > o ? rkey0[r] : o;
      o = (uint32_t)__shfl_xor((int)rkey1[r], mm, 64);
      rkey1[r] = rkey1[r] > o ? rkey1[r] : o;
    }
  }
  if (c31 == 0) {   // lanes 0 and 32
    #pragma unroll
    for (int r = 0; r < 16; ++r) {
      const int rr = (r & 3) + 8 * (r >> 2) + hi2 * 4;
      keys[cs * NROWS + rowbase + rr] = rkey0[r];
      keys[cs * NROWS + rowbase + 32 + rr] = rkey1[r];
    }
  }
}

// ---------------- Kernel C1: combine splits, exact f32 distance + log -------
__global__ __launch_bounds__(256) void kdist(const float* __restrict__ in,
                                             const float* __restrict__ inv,
                                             const uint32_t* __restrict__ keys,
                                             float* __restrict__ partial) {
  __shared__ float acc4[4];
  const int lane = threadIdx.x & 63;
  const int wave = threadIdx.x >> 6;
  const int row = blockIdx.x * 4 + wave;
  uint32_t bk = 0u; int bs = 0;
  #pragma unroll
  for (int s = 0; s < CSPLIT; ++s) {
    const uint32_t k = keys[s * NROWS + row];
    if (k > bk) { bk = k; bs = s; }
  }
  const int bi = bs * COLS_PER_SPLIT + 2047 - (int)(bk & 2047u);
  const float ii = inv[row], jj = inv[bi];
  const float4* pi = (const float4*)(in + (size_t)row * DIM + lane * 8);
  const float4* pj = (const float4*)(in + (size_t)bi * DIM + lane * 8);
  const float4 a0 = pi[0], a1 = pi[1], b0 = pj[0], b1 = pj[1];
  float d, ss = 0.0f;
  d = a0.x*ii - b0.x*jj + 1e-8f; ss += d*d;
  d = a0.y*ii - b0.y*jj + 1e-8f; ss += d*d;
  d = a0.z*ii - b0.z*jj + 1e-8f; ss += d*d;
  d = a0.w*ii - b0.w*jj + 1e-8f; ss += d*d;
  d = a1.x*ii - b1.x*jj + 1e-8f; ss += d*d;
  d = a1.y*ii - b1.y*jj + 1e-8f; ss += d*d;
  d = a1.z*ii - b1.z*jj + 1e-8f; ss += d*d;
  d = a1.w*ii - b1.w*jj + 1e-8f; ss += d*d;
  #pragma unroll
  for (int m = 32; m >= 1; m >>= 1) ss += __shfl_xor(ss, m, 64);
  if (lane == 0) acc4[wave] = logf(sqrtf(ss) + 1e-8f);
  __syncthreads();
  if (threadIdx.x == 0)
    partial[blockIdx.x] = acc4[0] + acc4[1] + acc4[2] + acc4[3];
}

// ---------------- Kernel C2: final reduce -> loss ---------------------------
__global__ __launch_bounds__(256) void kfinal(const float* __restrict__ partial,
                                              float* __restrict__ out) {
  __shared__ float acc4[4];
  const int lane = threadIdx.x & 63;
  const int wave = threadIdx.x >> 6;
  float s = 0.0f;
  for (int i = threadIdx.x; i < NROWS / 4; i += 256) s += partial[i];
  #pragma unroll
  for (int m = 32; m >= 1; m >>= 1) s += __shfl_xor(s, m, 64);
  if (lane == 0) acc4[wave] = s;
  __syncthreads();
  if (threadIdx.x == 0)
    out[0] = -(acc4[0] + acc4[1] + acc4[2] + acc4[3]) * (1.0f / (float)NROWS);
}

extern "C" void kernel_launch(void* const* d_in, const int* in_sizes, int n_in,
                              void* d_out, int out_size, void* d_ws, size_t ws_size,
                              hipStream_t stream) {
  const float* in = (const float*)d_in[0];
  char* ws = (char*)d_ws;
  signed char* xq   = (signed char*)(ws);                  //  8,388,608 B
  float*       inv  = (float*)(ws + 8388608);              //     65,536 B
  uint32_t*    keys = (uint32_t*)(ws + 8454144);           //    524,288 B
  float*       part = (float*)(ws + 8978432);              //     16,384 B

  knorm<<<NROWS / 4, 256, 0, stream>>>(in, xq, inv);
  kdots<<<(NROWS / BM) * CSPLIT, 256, 0, stream>>>(xq, keys);
  kdist<<<NROWS / 4, 256, 0, stream>>>(in, inv, keys, part);
  kfinal<<<1, 256, 0, stream>>>(part, (float*)d_out);
}

// Round 20
// 217.299 us; speedup vs baseline: 1.0273x; 1.0273x over previous
//
#include <hip/hip_runtime.h>
#include <stdint.h>

#define NROWS 16384
#define DIM 512
#define CSPLIT 8
#define COLS_PER_SPLIT (NROWS / CSPLIT)   // 2048
#define BM 256                            // rows per block (4 waves x 64)
#define NT 32                             // cols per tile
#define BK 256                            // k per K-step
#define NTILES (COLS_PER_SPLIT / NT)      // 64
#define PPT (DIM / BK)                    // 2 K-steps per tile
#define NPHASE (NTILES * PPT)             // 128
#define PMASK (NPHASE - 1)

using i32x4  = __attribute__((ext_vector_type(4))) int;
using i32x16 = __attribute__((ext_vector_type(16))) int;
using char8  = __attribute__((ext_vector_type(8))) signed char;

#define AS1 __attribute__((address_space(1)))
#define AS3 __attribute__((address_space(3)))

// ---------------- Kernel A: L2-normalize + FIXED-scale i8 quantize ----------
__global__ __launch_bounds__(256) void knorm(const float* __restrict__ in,
                                             signed char* __restrict__ xq,
                                             float* __restrict__ inv) {
  const int lane = threadIdx.x & 63;
  const int wave = threadIdx.x >> 6;
  const int row = blockIdx.x * 4 + wave;
  const float4* p = (const float4*)(in + (size_t)row * DIM + lane * 8);
  const float4 a = p[0], b = p[1];
  float ss = a.x*a.x + a.y*a.y + a.z*a.z + a.w*a.w
           + b.x*b.x + b.y*b.y + b.z*b.z + b.w*b.w;
  #pragma unroll
  for (int m = 32; m >= 1; m >>= 1) ss += __shfl_xor(ss, m, 64);
  const float iv = 1.0f / fmaxf(sqrtf(ss), 1e-8f);
  const float s508 = iv * 508.0f;
  char8 q;
  q[0] = (signed char)(int)rintf(fminf(fmaxf(a.x * s508, -127.f), 127.f));
  q[1] = (signed char)(int)rintf(fminf(fmaxf(a.y * s508, -127.f), 127.f));
  q[2] = (signed char)(int)rintf(fminf(fmaxf(a.z * s508, -127.f), 127.f));
  q[3] = (signed char)(int)rintf(fminf(fmaxf(a.w * s508, -127.f), 127.f));
  q[4] = (signed char)(int)rintf(fminf(fmaxf(b.x * s508, -127.f), 127.f));
  q[5] = (signed char)(int)rintf(fminf(fmaxf(b.y * s508, -127.f), 127.f));
  q[6] = (signed char)(int)rintf(fminf(fmaxf(b.z * s508, -127.f), 127.f));
  q[7] = (signed char)(int)rintf(fminf(fmaxf(b.w * s508, -127.f), 127.f));
  *(char8*)(xq + (size_t)row * DIM + lane * 8) = q;
  if (lane == 0) inv[row] = iv;
}

// ---------------- Kernel B: i8 Gram (32x32x32 MFMA) + integer argmax --------
// R19 skeleton with the bank-conflict-FIXED LDS layout:
//   byte(col, j) = col*256 + ((j ^ (col&7)) << 4)   (j = 16B k-chunk, 0..15)
// Read position (j^(col&7))&7 is a bijection over every aligned 8-lane group
// (R10's conflict-free property). Write: thread u -> col=u>>4, j=(u&15)^(col&7)
// — 16 consecutive threads cover one 256B column strip (coalesced).
__global__ __launch_bounds__(256, 2) void kdots(const signed char* __restrict__ xq,
                                                uint32_t* __restrict__ keys) {
  const int tid  = threadIdx.x;
  const int lane = tid & 63;
  const int wave = tid >> 6;
  const int bx = blockIdx.x;
  const int cs = bx & (CSPLIT - 1);     // same-cs blocks land on same XCD (%8)
  const int rb = bx >> 3;
  const int rowbase  = rb * BM + wave * 64;
  const int colsplit = cs * COLS_PER_SPLIT;
  // diag falls in tiles td0, td0+1 (32-col tiles vs 64-row wave), or never
  const int td0 = ((rowbase >> 11) == cs) ? ((rowbase - colsplit) >> 5)
                                          : -0x40000000;
  const int c31 = lane & 31;
  const int hi2 = lane >> 5;            // 0/1
  const int rb0 = rowbase + hi2 * 4;          // rf=0 row base for this lane
  const int rb1 = rowbase + 32 + hi2 * 4;     // rf=1

  __shared__ signed char lds[4][NT * BK];   // 4 x 8 KB

  // ---- A fragments: 2 rowfrags x 16 kfrags(K=32) x 4 regs = 128 VGPR ----
  // layout per mfma_32x32x32_i8: row = lane&31, k = (lane>>5)*16 + e
  i32x4 areg[2][16];
  #pragma unroll
  for (int rf = 0; rf < 2; ++rf) {
    const signed char* ap =
        xq + (size_t)(rowbase + rf * 32 + c31) * DIM + hi2 * 16;
    #pragma unroll
    for (int kf = 0; kf < 16; ++kf)
      areg[rf][kf] = *(const i32x4*)(ap + kf * 32);
  }

  uint32_t rkey0[16], rkey1[16];
  #pragma unroll
  for (int r = 0; r < 16; ++r) { rkey0[r] = 0u; rkey1[r] = 0u; }

  i32x16 acc0, acc1;   // zero-C'd at each tile's kb0; EPI reads next tile

  // stage one 8 KB buffer (32 cols x 256B): 2 global_load_lds(16B)/thread.
  // u -> col = u>>4, jslot = u&15, j = jslot ^ (col&7); dest linear u*16.
  auto STAGE = [&](int buf, int p) {
    const int tt = p >> 1, kb2 = p & 1;
    #pragma unroll
    for (int h = 0; h < 2; ++h) {
      const int u = h * 256 + tid;
      const int col = u >> 4;
      const int j = (u & 15) ^ (col & 7);
      const signed char* g = xq + (size_t)(colsplit + tt * NT + col) * DIM
                           + kb2 * BK + (j << 4);
      char* l = ((char*)&lds[buf][0]) + u * 16;
      __builtin_amdgcn_global_load_lds((AS1 const void*)g, (AS3 void*)l, 16, 0, 0);
    }
  };

  __syncthreads();   // drains areg loads (vmcnt -> 0)
  STAGE(0, 0); STAGE(1, 1); STAGE(2, 2);   // depth-3 prologue: 6 outstanding

  // ds_read offsets: lane reads col=c31, chunk j = kf*2 + hi2.
  // addr = c31*256 + ((j ^ (c31&7))<<4);  kf and kf+4 differ by +128 (bit 3).
  const int e  = c31 & 7;
  const int rbase = c31 * 256;
  const int r0 = rbase + (((0 + hi2) ^ e) << 4);   // kf&3 == 0
  const int r1 = rbase + (((2 + hi2) ^ e) << 4);   // kf&3 == 1
  const int r2 = rbase + (((4 + hi2) ^ e) << 4);   // kf&3 == 2
  const int r3 = rbase + (((6 + hi2) ^ e) << 4);   // kf&3 == 3

#define EPI(ACC, RK, RBQ)                                                      \
  do {                                                                         \
    const uint32_t k0c = 0x80000000u + 2047u - (uint32_t)(pcolb + c31);        \
    _Pragma("unroll")                                                          \
    for (int r = 0; r < 16; ++r) {                                             \
      uint32_t key = ((uint32_t)(ACC[r] >> 3) << 11) + k0c;                    \
      if (dg && (gcolp == (RBQ) + (r & 3) + 8 * (r >> 2))) key = 0u;           \
      RK[r] = RK[r] > key ? RK[r] : key;                                       \
    }                                                                          \
  } while (0)

// 4 MFMAs: both accs accumulate kfrag KA (FA) then KA+1 (FB)
#define CL4(KA, FA, FB)                                                        \
  __builtin_amdgcn_s_setprio(1);                                               \
  acc0 = __builtin_amdgcn_mfma_i32_32x32x32_i8(areg[0][KA], FA, acc0, 0,0,0);  \
  acc1 = __builtin_amdgcn_mfma_i32_32x32x32_i8(areg[1][KA], FA, acc1, 0,0,0);  \
  acc0 = __builtin_amdgcn_mfma_i32_32x32x32_i8(areg[0][(KA)+1], FB, acc0, 0,0,0);\
  acc1 = __builtin_amdgcn_mfma_i32_32x32x32_i8(areg[1][(KA)+1], FB, acc1, 0,0,0);\
  __builtin_amdgcn_s_setprio(0);

#define WAITB                                                                  \
  asm volatile("s_waitcnt vmcnt(4)" ::: "memory");                             \
  __builtin_amdgcn_s_barrier();                                                \
  asm volatile("" ::: "memory");

// kb=0 K-step of tile T reading buf B: zero-C + EPI of tile T-1 interleaved
#define KSTEP0(T, B, SB, SP)                                                   \
  {                                                                            \
    WAITB                                                                      \
    STAGE(SB, (SP) & PMASK);                                                   \
    const char* base = (const char*)&lds[B][0];                                \
    i32x4 fA = *(const i32x4*)(base + r0);                                     \
    i32x4 fB = *(const i32x4*)(base + r1);                                     \
    i32x4 fC = *(const i32x4*)(base + r2);                                     \
    i32x4 fD = *(const i32x4*)(base + r3);                                     \
    const int pcolb = ((T) - 1) * NT;                                          \
    const bool dg = (unsigned)(((T) - 1) - td0) <= 1u;                         \
    const int gcolp = colsplit + pcolb + c31;                                  \
    if (T) EPI(acc0, rkey0, rb0);                                              \
    __builtin_amdgcn_s_setprio(1);                                             \
    acc0 = __builtin_amdgcn_mfma_i32_32x32x32_i8(areg[0][0], fA, Z16, 0,0,0);  \
    acc0 = __builtin_amdgcn_mfma_i32_32x32x32_i8(areg[0][1], fB, acc0, 0,0,0); \
    __builtin_amdgcn_s_setprio(0);                                             \
    if (T) EPI(acc1, rkey1, rb1);                                              \
    __builtin_amdgcn_s_setprio(1);                                             \
    acc1 = __builtin_amdgcn_mfma_i32_32x32x32_i8(areg[1][0], fA, Z16, 0,0,0);  \
    acc1 = __builtin_amdgcn_mfma_i32_32x32x32_i8(areg[1][1], fB, acc1, 0,0,0); \
    __builtin_amdgcn_s_setprio(0);                                             \
    fA = *(const i32x4*)(base + r0 + 128);                                     \
    fB = *(const i32x4*)(base + r1 + 128);                                     \
    CL4(2, fC, fD)                                                             \
    fC = *(const i32x4*)(base + r2 + 128);                                     \
    fD = *(const i32x4*)(base + r3 + 128);                                     \
    CL4(4, fA, fB)                                                             \
    CL4(6, fC, fD)                                                             \
  }

// kb=1 K-step reading buf B (kfrags 8..15)
#define KSTEP1(B, SB, SP)                                                      \
  {                                                                            \
    WAITB                                                                      \
    STAGE(SB, (SP) & PMASK);                                                   \
    const char* base = (const char*)&lds[B][0];                                \
    i32x4 fA = *(const i32x4*)(base + r0);                                     \
    i32x4 fB = *(const i32x4*)(base + r1);                                     \
    i32x4 fC = *(const i32x4*)(base + r2);                                     \
    i32x4 fD = *(const i32x4*)(base + r3);                                     \
    CL4(8, fA, fB)                                                             \
    fA = *(const i32x4*)(base + r0 + 128);                                     \
    fB = *(const i32x4*)(base + r1 + 128);                                     \
    CL4(10, fC, fD)                                                            \
    fC = *(const i32x4*)(base + r2 + 128);                                     \
    fD = *(const i32x4*)(base + r3 + 128);                                     \
    CL4(12, fA, fB)                                                            \
    CL4(14, fC, fD)                                                            \
  }

  const i32x16 Z16 = {0,0,0,0,0,0,0,0,0,0,0,0,0,0,0,0};

  for (int tp = 0; tp < NTILES; tp += 2) {
    const int P = 2 * tp;                 // P % 4 == 0
    // ---- tile tp: phases P (buf0), P+1 (buf1) ----
    KSTEP0(tp, 0, 3, P + 3)
    KSTEP1(1, 0, P + 4)
    // ---- tile tp+1: phases P+2 (buf2), P+3 (buf3) ----
    KSTEP0(tp + 1, 2, 1, P + 5)
    KSTEP1(3, 2, P + 6)
  }
  // ---- final epilogue for tile NTILES-1 ----
  {
    const int pcolb = (NTILES - 1) * NT;
    const bool dg = (unsigned)((NTILES - 1) - td0) <= 1u;
    const int gcolp = colsplit + pcolb + c31;
    EPI(acc0, rkey0, rb0);
    EPI(acc1, rkey1, rb1);
  }
#undef KSTEP0
#undef KSTEP1
#undef WAITB
#undef CL4
#undef EPI

  // ---- cross-lane key max over the 32-lane col dimension -------------------
  #pragma unroll
  for (int mm = 1; mm <= 16; mm <<= 1) {
    #pragma unroll
    for (int r = 0; r < 16; ++r) {
      uint32_t o = (uint32_t)__shfl_xor((int)rkey0[r], mm, 64);
      rkey0[r] = rkey0[r] > o ? rkey0[r] : o;
      o = (uint32_t)__shfl_xor((int)rkey1[r], mm, 64);
      rkey1[r] = rkey1[r] > o ? rkey1[r] : o;
    }
  }
  if (c31 == 0) {   // lanes 0 and 32
    #pragma unroll
    for (int r = 0; r < 16; ++r) {
      const int rr = (r & 3) + 8 * (r >> 2) + hi2 * 4;
      keys[cs * NROWS + rowbase + rr] = rkey0[r];
      keys[cs * NROWS + rowbase + 32 + rr] = rkey1[r];
    }
  }
}

// ---------------- Kernel C1: combine splits, exact f32 distance + log -------
__global__ __launch_bounds__(256) void kdist(const float* __restrict__ in,
                                             const float* __restrict__ inv,
                                             const uint32_t* __restrict__ keys,
                                             float* __restrict__ partial) {
  __shared__ float acc4[4];
  const int lane = threadIdx.x & 63;
  const int wave = threadIdx.x >> 6;
  const int row = blockIdx.x * 4 + wave;
  uint32_t bk = 0u; int bs = 0;
  #pragma unroll
  for (int s = 0; s < CSPLIT; ++s) {
    const uint32_t k = keys[s * NROWS + row];
    if (k > bk) { bk = k; bs = s; }
  }
  const int bi = bs * COLS_PER_SPLIT + 2047 - (int)(bk & 2047u);
  const float ii = inv[row], jj = inv[bi];
  const float4* pi = (const float4*)(in + (size_t)row * DIM + lane * 8);
  const float4* pj = (const float4*)(in + (size_t)bi * DIM + lane * 8);
  const float4 a0 = pi[0], a1 = pi[1], b0 = pj[0], b1 = pj[1];
  float d, ss = 0.0f;
  d = a0.x*ii - b0.x*jj + 1e-8f; ss += d*d;
  d = a0.y*ii - b0.y*jj + 1e-8f; ss += d*d;
  d = a0.z*ii - b0.z*jj + 1e-8f; ss += d*d;
  d = a0.w*ii - b0.w*jj + 1e-8f; ss += d*d;
  d = a1.x*ii - b1.x*jj + 1e-8f; ss += d*d;
  d = a1.y*ii - b1.y*jj + 1e-8f; ss += d*d;
  d = a1.z*ii - b1.z*jj + 1e-8f; ss += d*d;
  d = a1.w*ii - b1.w*jj + 1e-8f; ss += d*d;
  #pragma unroll
  for (int m = 32; m >= 1; m >>= 1) ss += __shfl_xor(ss, m, 64);
  if (lane == 0) acc4[wave] = logf(sqrtf(ss) + 1e-8f);
  __syncthreads();
  if (threadIdx.x == 0)
    partial[blockIdx.x] = acc4[0] + acc4[1] + acc4[2] + acc4[3];
}

// ---------------- Kernel C2: final reduce -> loss ---------------------------
__global__ __launch_bounds__(256) void kfinal(const float* __restrict__ partial,
                                              float* __restrict__ out) {
  __shared__ float acc4[4];
  const int lane = threadIdx.x & 63;
  const int wave = threadIdx.x >> 6;
  float s = 0.0f;
  for (int i = threadIdx.x; i < NROWS / 4; i += 256) s += partial[i];
  #pragma unroll
  for (int m = 32; m >= 1; m >>= 1) s += __shfl_xor(s, m, 64);
  if (lane == 0) acc4[wave] = s;
  __syncthreads();
  if (threadIdx.x == 0)
    out[0] = -(acc4[0] + acc4[1] + acc4[2] + acc4[3]) * (1.0f / (float)NROWS);
}

extern "C" void kernel_launch(void* const* d_in, const int* in_sizes, int n_in,
                              void* d_out, int out_size, void* d_ws, size_t ws_size,
                              hipStream_t stream) {
  const float* in = (const float*)d_in[0];
  char* ws = (char*)d_ws;
  signed char* xq   = (signed char*)(ws);                  //  8,388,608 B
  float*       inv  = (float*)(ws + 8388608);              //     65,536 B
  uint32_t*    keys = (uint32_t*)(ws + 8454144);           //    524,288 B
  float*       part = (float*)(ws + 8978432);              //     16,384 B

  knorm<<<NROWS / 4, 256, 0, stream>>>(in, xq, inv);
  kdots<<<(NROWS / BM) * CSPLIT, 256, 0, stream>>>(xq, keys);
  kdist<<<NROWS / 4, 256, 0, stream>>>(in, inv, keys, part);
  kfinal<<<1, 256, 0, stream>>>(part, (float*)d_out);
}

// Round 21
// 136.852 us; speedup vs baseline: 1.6312x; 1.5878x over previous
//
#include <hip/hip_runtime.h>
#include <stdint.h>

#define NROWS 16384
#define DIM 512
#define CSPLIT 8
#define COLS_PER_SPLIT (NROWS / CSPLIT)   // 2048
#define BM 256                            // rows per block (4 waves x 64)
#define NT 64                             // cols per tile
#define BK 128                            // k per K-step
#define NTILES (COLS_PER_SPLIT / NT)      // 32
#define PPT (DIM / BK)                    // 4 K-steps per tile
#define NPHASE (NTILES * PPT)             // 128

using i32x4 = __attribute__((ext_vector_type(4))) int;
using char8 = __attribute__((ext_vector_type(8))) signed char;

#define AS1 __attribute__((address_space(1)))
#define AS3 __attribute__((address_space(3)))

// ---------------- Kernel A: L2-normalize + FIXED-scale i8 quantize ----------
// q = round(clamp(x_norm * 508, -127, 127));  508 = 127/0.25.  The global
// scale is constant, so argmax over columns reduces to integer argmax of idot.
__global__ __launch_bounds__(256) void knorm(const float* __restrict__ in,
                                             signed char* __restrict__ xq,
                                             float* __restrict__ inv) {
  const int lane = threadIdx.x & 63;
  const int wave = threadIdx.x >> 6;
  const int row = blockIdx.x * 4 + wave;
  const float4* p = (const float4*)(in + (size_t)row * DIM + lane * 8);
  const float4 a = p[0], b = p[1];
  float ss = a.x*a.x + a.y*a.y + a.z*a.z + a.w*a.w
           + b.x*b.x + b.y*b.y + b.z*b.z + b.w*b.w;
  #pragma unroll
  for (int m = 32; m >= 1; m >>= 1) ss += __shfl_xor(ss, m, 64);
  const float iv = 1.0f / fmaxf(sqrtf(ss), 1e-8f);
  const float s508 = iv * 508.0f;
  char8 q;
  q[0] = (signed char)(int)rintf(fminf(fmaxf(a.x * s508, -127.f), 127.f));
  q[1] = (signed char)(int)rintf(fminf(fmaxf(a.y * s508, -127.f), 127.f));
  q[2] = (signed char)(int)rintf(fminf(fmaxf(a.z * s508, -127.f), 127.f));
  q[3] = (signed char)(int)rintf(fminf(fmaxf(a.w * s508, -127.f), 127.f));
  q[4] = (signed char)(int)rintf(fminf(fmaxf(b.x * s508, -127.f), 127.f));
  q[5] = (signed char)(int)rintf(fminf(fmaxf(b.y * s508, -127.f), 127.f));
  q[6] = (signed char)(int)rintf(fminf(fmaxf(b.z * s508, -127.f), 127.f));
  q[7] = (signed char)(int)rintf(fminf(fmaxf(b.w * s508, -127.f), 127.f));
  *(char8*)(xq + (size_t)row * DIM + lane * 8) = q;
  if (lane == 0) inv[row] = iv;
}

// ---------------- Kernel B: i8 Gram + fused integer argmax ------------------
// Verified best (R10/R18, 137.1 us total): 4 waves x 64 rows, A register-
// resident (128 VGPR), 4 x 8 KB LDS buffers, depth-3 prefetch, counted
// vmcnt(4) + ONE barrier per K-step, cluster-pipelined compiler-scheduled LDS
// reads, setprio around MFMA clusters, integer packed keys (3 VALU/value),
// zero-C first K-step, prev-tile epilogue interleaved into kb=0's clusters.
__global__ __launch_bounds__(256, 2) void kdots(const signed char* __restrict__ xq,
                                                uint32_t* __restrict__ keys) {
  const int tid  = threadIdx.x;
  const int lane = tid & 63;
  const int wave = tid >> 6;
  const int bx = blockIdx.x;
  const int cs = bx & (CSPLIT - 1);     // same-cs blocks land on same XCD (%8)
  const int rb = bx >> 3;
  const int rowbase  = rb * BM + wave * 64;
  const int colsplit = cs * COLS_PER_SPLIT;
  // the one tile (per wave) containing diagonal elements, or -1
  const int tdiag = ((rowbase >> 11) == cs) ? ((rowbase - colsplit) >> 6) : -1;
  const int c15 = lane & 15;
  const int hi4 = (lane >> 4) * 4;

  __shared__ signed char lds[4][NT * BK];   // 4 x 8 KB

  // ---- A fragments in registers: 4 rowfrags x 8 kfrags(K=64) = 128 VGPR ----
  i32x4 areg[4][8];
  #pragma unroll
  for (int rf = 0; rf < 4; ++rf) {
    const signed char* ap =
        xq + (size_t)(rowbase + rf * 16 + c15) * DIM + ((lane >> 4) * 16);
    #pragma unroll
    for (int kf = 0; kf < 8; ++kf)
      areg[rf][kf] = *(const i32x4*)(ap + kf * 64);
  }

  uint32_t rkey[4][4];
  #pragma unroll
  for (int rf = 0; rf < 4; ++rf)
    #pragma unroll
    for (int r = 0; r < 4; ++r) rkey[rf][r] = 0u;

  i32x4 acc[4][4];   // written by zero-C clusters each tile; read next tile

  // stage one 8 KB buffer: 2 global_load_lds(16B) per thread.
  // LDS layout [col][8 x 16B k-chunks], source k-chunk pre-swizzled k16^(col&7).
  auto STAGE = [&](int buf, int p) {
    const int tt = p >> 2, kb2 = p & 3;
    #pragma unroll
    for (int h = 0; h < 2; ++h) {
      const int u = h * 256 + tid;
      const int col = u >> 3;
      const int k16 = u & 7;
      const signed char* g = xq + (size_t)(colsplit + tt * NT + col) * DIM
                           + kb2 * BK + ((k16 ^ (col & 7)) << 4);
      char* l = ((char*)&lds[buf][0]) + u * 16;
      __builtin_amdgcn_global_load_lds((AS1 const void*)g, (AS3 void*)l, 16, 0, 0);
    }
  };

  __syncthreads();   // drains areg loads (vmcnt -> 0)
  STAGE(0, 0); STAGE(1, 1); STAGE(2, 2);   // depth-3 prologue: 6 outstanding

  // ds_read offsets: cf*2048 + c15*128 + ((kk*4+hi)^(c15&7))*16; kk=1 = ^64
  const int ro0 = c15 * 128 + (((lane >> 4) ^ (lane & 7)) << 4);
  const int ro1 = ro0 ^ 64;

// integer packed-key epilogue chunk for prev tile's acc[*][Q] (Q literal)
#define EPI(Q, COLB0P, DG)                                                     \
  do {                                                                         \
    const uint32_t k0c =                                                       \
        0x80000000u + 2047u - (uint32_t)((COLB0P) + (Q) * 16 + c15);           \
    _Pragma("unroll")                                                          \
    for (int rf = 0; rf < 4; ++rf) {                                           \
      _Pragma("unroll")                                                        \
      for (int r = 0; r < 4; ++r) {                                            \
        const int t1 = acc[rf][Q][r] >> 3;                                     \
        uint32_t key = ((uint32_t)t1 << 11) + k0c;                             \
        if (rf == (Q) && (DG)) key = (c15 == hi4 + r) ? 0u : key;              \
        rkey[rf][r] = rkey[rf][r] > key ? rkey[rf][r] : key;                   \
      }                                                                        \
    }                                                                          \
  } while (0)

#define CLUSTER(Q, BA, BB)                                                     \
  __builtin_amdgcn_s_setprio(1);                                              \
  acc[0][Q] = __builtin_amdgcn_mfma_i32_16x16x64_i8(a0, BA, acc[0][Q], 0,0,0);\
  acc[1][Q] = __builtin_amdgcn_mfma_i32_16x16x64_i8(a1, BA, acc[1][Q], 0,0,0);\
  acc[2][Q] = __builtin_amdgcn_mfma_i32_16x16x64_i8(a2, BA, acc[2][Q], 0,0,0);\
  acc[3][Q] = __builtin_amdgcn_mfma_i32_16x16x64_i8(a3, BA, acc[3][Q], 0,0,0);\
  acc[0][Q] = __builtin_amdgcn_mfma_i32_16x16x64_i8(a4, BB, acc[0][Q], 0,0,0);\
  acc[1][Q] = __builtin_amdgcn_mfma_i32_16x16x64_i8(a5, BB, acc[1][Q], 0,0,0);\
  acc[2][Q] = __builtin_amdgcn_mfma_i32_16x16x64_i8(a6, BB, acc[2][Q], 0,0,0);\
  acc[3][Q] = __builtin_amdgcn_mfma_i32_16x16x64_i8(a7, BB, acc[3][Q], 0,0,0);\
  __builtin_amdgcn_s_setprio(0);

#define CLUSTERZ(Q, BA, BB)                                                    \
  __builtin_amdgcn_s_setprio(1);                                              \
  acc[0][Q] = __builtin_amdgcn_mfma_i32_16x16x64_i8(a0, BA, (i32x4){0,0,0,0}, 0,0,0);\
  acc[1][Q] = __builtin_amdgcn_mfma_i32_16x16x64_i8(a1, BA, (i32x4){0,0,0,0}, 0,0,0);\
  acc[2][Q] = __builtin_amdgcn_mfma_i32_16x16x64_i8(a2, BA, (i32x4){0,0,0,0}, 0,0,0);\
  acc[3][Q] = __builtin_amdgcn_mfma_i32_16x16x64_i8(a3, BA, (i32x4){0,0,0,0}, 0,0,0);\
  acc[0][Q] = __builtin_amdgcn_mfma_i32_16x16x64_i8(a4, BB, acc[0][Q], 0,0,0);\
  acc[1][Q] = __builtin_amdgcn_mfma_i32_16x16x64_i8(a5, BB, acc[1][Q], 0,0,0);\
  acc[2][Q] = __builtin_amdgcn_mfma_i32_16x16x64_i8(a6, BB, acc[2][Q], 0,0,0);\
  acc[3][Q] = __builtin_amdgcn_mfma_i32_16x16x64_i8(a7, BB, acc[3][Q], 0,0,0);\
  __builtin_amdgcn_s_setprio(0);

  for (int t = 0; t < NTILES; ++t) {
    const int colb0p = (t - 1) * NT;
    const bool dg = ((t - 1) == tdiag);
    // ---- K-step kb=0: zero-C clusters + interleaved prev-tile epilogue ----
    asm volatile("s_waitcnt vmcnt(4)" ::: "memory");
    __builtin_amdgcn_s_barrier();
    asm volatile("" ::: "memory");
    STAGE(3, (t * PPT + 3) & (NPHASE - 1));
    {
      const char* base = (const char*)&lds[0][0];
      const i32x4 a0 = areg[0][0], a1 = areg[1][0];
      const i32x4 a2 = areg[2][0], a3 = areg[3][0];
      const i32x4 a4 = areg[0][1], a5 = areg[1][1];
      const i32x4 a6 = areg[2][1], a7 = areg[3][1];
      i32x4 b0a = *(const i32x4*)(base + ro0);
      i32x4 b0b = *(const i32x4*)(base + ro1);
      i32x4 b1a = *(const i32x4*)(base + 2048 + ro0);
      i32x4 b1b = *(const i32x4*)(base + 2048 + ro1);
      if (t) EPI(0, colb0p, dg);
      CLUSTERZ(0, b0a, b0b)
      b0a = *(const i32x4*)(base + 4096 + ro0);
      b0b = *(const i32x4*)(base + 4096 + ro1);
      if (t) EPI(1, colb0p, dg);
      CLUSTERZ(1, b1a, b1b)
      b1a = *(const i32x4*)(base + 6144 + ro0);
      b1b = *(const i32x4*)(base + 6144 + ro1);
      if (t) EPI(2, colb0p, dg);
      CLUSTERZ(2, b0a, b0b)
      if (t) EPI(3, colb0p, dg);
      CLUSTERZ(3, b1a, b1b)
    }
    // ---- K-steps kb=1..3: accumulating clusters ----
    #pragma unroll
    for (int kb = 1; kb < PPT; ++kb) {
      asm volatile("s_waitcnt vmcnt(4)" ::: "memory");
      __builtin_amdgcn_s_barrier();
      asm volatile("" ::: "memory");
      STAGE((kb + 3) & 3, (t * PPT + kb + 3) & (NPHASE - 1));
      const char* base = (const char*)&lds[kb & 3][0];
      const i32x4 a0 = areg[0][kb*2],   a1 = areg[1][kb*2];
      const i32x4 a2 = areg[2][kb*2],   a3 = areg[3][kb*2];
      const i32x4 a4 = areg[0][kb*2+1], a5 = areg[1][kb*2+1];
      const i32x4 a6 = areg[2][kb*2+1], a7 = areg[3][kb*2+1];
      i32x4 b0a = *(const i32x4*)(base + ro0);
      i32x4 b0b = *(const i32x4*)(base + ro1);
      i32x4 b1a = *(const i32x4*)(base + 2048 + ro0);
      i32x4 b1b = *(const i32x4*)(base + 2048 + ro1);
      CLUSTER(0, b0a, b0b)
      b0a = *(const i32x4*)(base + 4096 + ro0);
      b0b = *(const i32x4*)(base + 4096 + ro1);
      CLUSTER(1, b1a, b1b)
      b1a = *(const i32x4*)(base + 6144 + ro0);
      b1b = *(const i32x4*)(base + 6144 + ro1);
      CLUSTER(2, b0a, b0b)
      CLUSTER(3, b1a, b1b)
    }
  }
  // ---- final epilogue for tile NTILES-1 ----
  {
    const int colb0p = (NTILES - 1) * NT;
    const bool dg = ((NTILES - 1) == tdiag);
    EPI(0, colb0p, dg);
    EPI(1, colb0p, dg);
    EPI(2, colb0p, dg);
    EPI(3, colb0p, dg);
  }
#undef CLUSTER
#undef CLUSTERZ
#undef EPI

  // ---- cross-lane key max within each 16-lane group ------------------------
  #pragma unroll
  for (int m = 1; m <= 8; m <<= 1) {
    #pragma unroll
    for (int rf = 0; rf < 4; ++rf) {
      #pragma unroll
      for (int r = 0; r < 4; ++r) {
        const uint32_t ok =
            (uint32_t)__shfl_xor((int)rkey[rf][r], m, 64);
        rkey[rf][r] = rkey[rf][r] > ok ? rkey[rf][r] : ok;
      }
    }
  }
  if (c15 == 0) {
    #pragma unroll
    for (int rf = 0; rf < 4; ++rf) {
      #pragma unroll
      for (int r = 0; r < 4; ++r) {
        const int grow = rowbase + rf * 16 + hi4 + r;
        keys[cs * NROWS + grow] = rkey[rf][r];
      }
    }
  }
}

// ---------------- Kernel C1: combine splits, exact f32 distance + log -------
__global__ __launch_bounds__(256) void kdist(const float* __restrict__ in,
                                             const float* __restrict__ inv,
                                             const uint32_t* __restrict__ keys,
                                             float* __restrict__ partial) {
  __shared__ float acc4[4];
  const int lane = threadIdx.x & 63;
  const int wave = threadIdx.x >> 6;
  const int row = blockIdx.x * 4 + wave;
  uint32_t bk = 0u; int bs = 0;
  #pragma unroll
  for (int s = 0; s < CSPLIT; ++s) {
    const uint32_t k = keys[s * NROWS + row];
    if (k > bk) { bk = k; bs = s; }
  }
  const int bi = bs * COLS_PER_SPLIT + 2047 - (int)(bk & 2047u);
  const float ii = inv[row], jj = inv[bi];
  const float4* pi = (const float4*)(in + (size_t)row * DIM + lane * 8);
  const float4* pj = (const float4*)(in + (size_t)bi * DIM + lane * 8);
  const float4 a0 = pi[0], a1 = pi[1], b0 = pj[0], b1 = pj[1];
  float d, ss = 0.0f;
  d = a0.x*ii - b0.x*jj + 1e-8f; ss += d*d;
  d = a0.y*ii - b0.y*jj + 1e-8f; ss += d*d;
  d = a0.z*ii - b0.z*jj + 1e-8f; ss += d*d;
  d = a0.w*ii - b0.w*jj + 1e-8f; ss += d*d;
  d = a1.x*ii - b1.x*jj + 1e-8f; ss += d*d;
  d = a1.y*ii - b1.y*jj + 1e-8f; ss += d*d;
  d = a1.z*ii - b1.z*jj + 1e-8f; ss += d*d;
  d = a1.w*ii - b1.w*jj + 1e-8f; ss += d*d;
  #pragma unroll
  for (int m = 32; m >= 1; m >>= 1) ss += __shfl_xor(ss, m, 64);
  if (lane == 0) acc4[wave] = logf(sqrtf(ss) + 1e-8f);
  __syncthreads();
  if (threadIdx.x == 0)
    partial[blockIdx.x] = acc4[0] + acc4[1] + acc4[2] + acc4[3];
}

// ---------------- Kernel C2: final reduce -> loss ---------------------------
__global__ __launch_bounds__(256) void kfinal(const float* __restrict__ partial,
                                              float* __restrict__ out) {
  __shared__ float acc4[4];
  const int lane = threadIdx.x & 63;
  const int wave = threadIdx.x >> 6;
  float s = 0.0f;
  for (int i = threadIdx.x; i < NROWS / 4; i += 256) s += partial[i];
  #pragma unroll
  for (int m = 32; m >= 1; m >>= 1) s += __shfl_xor(s, m, 64);
  if (lane == 0) acc4[wave] = s;
  __syncthreads();
  if (threadIdx.x == 0)
    out[0] = -(acc4[0] + acc4[1] + acc4[2] + acc4[3]) * (1.0f / (float)NROWS);
}

extern "C" void kernel_launch(void* const* d_in, const int* in_sizes, int n_in,
                              void* d_out, int out_size, void* d_ws, size_t ws_size,
                              hipStream_t stream) {
  const float* in = (const float*)d_in[0];
  char* ws = (char*)d_ws;
  signed char* xq   = (signed char*)(ws);                  //  8,388,608 B
  float*       inv  = (float*)(ws + 8388608);              //     65,536 B
  uint32_t*    keys = (uint32_t*)(ws + 8454144);           //    524,288 B
  float*       part = (float*)(ws + 8978432);              //     16,384 B

  knorm<<<NROWS / 4, 256, 0, stream>>>(in, xq, inv);
  kdots<<<(NROWS / BM) * CSPLIT, 256, 0, stream>>>(xq, keys);
  kdist<<<NROWS / 4, 256, 0, stream>>>(in, inv, keys, part);
  kfinal<<<1, 256, 0, stream>>>(part, (float*)d_out);
}